// Round 7
// baseline (12892.778 us; speedup 1.0000x reference)
//
#include <hip/hip_runtime.h>

#define NB 4096
#define ND 64
#define NH 256
#define NT 50
#define ROWS 8
#define THREADS 512
#define GRID (NB / ROWS)   // 512 blocks -> 2 per CU at <=112 VGPR

#define YIS 68   // yi row stride (floats); 272B, 16B-aligned quads
#define ZS  260  // z row stride (floats); 1040B, 16B-aligned quads
#define RS  65   // sRed row stride (floats)

__device__ __forceinline__ float fast_tanh(float x) {
  // tanh(x) = 1 - 2/(exp(2x)+1); safe at +-inf
  float e = __expf(2.0f * x);
  return 1.0f - 2.0f * __builtin_amdgcn_rcpf(e + 1.0f);
}

// quad-perm DPP butterfly add (VALU pipe, NOT the LDS pipe like __shfl)
template <int CTRL>
__device__ __forceinline__ float dpp_add(float x) {
  int s = __builtin_amdgcn_update_dpp(0, __float_as_int(x), CTRL, 0xF, 0xF, true);
  return x + __int_as_float(s);
}
#define DPP_XOR1 0xB1  // quad_perm [1,0,3,2]
#define DPP_XOR2 0x4E  // quad_perm [2,3,0,1]

extern "C" __global__
__attribute__((amdgpu_flat_work_group_size(THREADS, THREADS)))
__attribute__((amdgpu_waves_per_eu(2, 4)))   // proven no-spill point (r5)
void ode_kernel(const float* __restrict__ y0,
                const float* __restrict__ tt,
                const float* __restrict__ W1,
                const float* __restrict__ b1,
                const float* __restrict__ W2,
                const float* __restrict__ b2,
                float* __restrict__ out)
{
  __shared__ float sYI[ROWS * YIS];      // 2176 B
  __shared__ float sZ[ROWS * ZS];        // 8320 B
  __shared__ float sRed[4 * ROWS * RS];  // 8320 B   (18.8 KB total)

  const int tid = threadIdx.x;
  // owner/state role: wave wv = state row, lane d = dim
  const int wv = tid >> 6;
  const int d  = tid & 63;
  const int row = (int)blockIdx.x * ROWS + wv;
  // GEMM1 role: j-pair {jp, jp+128} x dim-quarter dg (dims 16dg..16dg+15)
  const int jp = tid >> 2;
  const int dg = tid & 3;
  // GEMM2 role: d-pair {2dp, 2dp+1} x j-chunk c (j's 16c..16c+15)
  // bits: c_hi = wv>>1 (wave-uniform), c_lo = tid&3 (quad), dp = (tid>>2)&31
  const int c_lo = tid & 3;
  const int c_hi = wv >> 1;
  const int c    = c_hi * 4 + c_lo;
  const int dp   = (tid >> 2) & 31;

  // W1 slices in registers: w1a = column jp, w1b = column jp+128 (16 dims each)
  float w1a[16], w1b[16];
#pragma unroll
  for (int dd = 0; dd < 16; ++dd) {
    w1a[dd] = W1[(dg * 16 + dd) * NH + jp];
    w1b[dd] = W1[(dg * 16 + dd) * NH + jp + 128];
  }
  const float b1a = b1[jp];
  const float b1b = b1[jp + 128];

  // W2 slices in registers: rows 16c..16c+15, cols 2dp and 2dp+1
  float w2a[16], w2b[16];
#pragma unroll
  for (int jj = 0; jj < 16; ++jj) {
    w2a[jj] = W2[(c * 16 + jj) * ND + 2 * dp];
    w2b[jj] = W2[(c * 16 + jj) * ND + 2 * dp + 1];
  }
  const float b2d = b2[d];

  // state: y[row][d]
  float y = y0[row * ND + d];
  out[row * ND + d] = y;

  // f(yi) = tanh(yi @ W1 + b1) @ W2 + b2, scalar slice per owner thread.
  auto feval = [&](float yiv) -> float {
    sYI[wv * YIS + d] = yiv;
    __syncthreads();                      // B_a: yi visible; sZ/sRed writable

    // ---- GEMM1: z[{jp,jp+128}][r] partial over 16 dims, 8 FMAs per quad ----
    float z0[ROWS], z1[ROWS];
#pragma unroll
    for (int r = 0; r < ROWS; ++r) { z0[r] = 0.0f; z1[r] = 0.0f; }
#pragma unroll
    for (int r = 0; r < ROWS; ++r) {
#pragma unroll
      for (int q = 0; q < 4; ++q) {
        const float4 a = *(const float4*)&sYI[r * YIS + dg * 16 + 4 * q];
        z0[r] = fmaf(a.x, w1a[4*q+0], z0[r]); z1[r] = fmaf(a.x, w1b[4*q+0], z1[r]);
        z0[r] = fmaf(a.y, w1a[4*q+1], z0[r]); z1[r] = fmaf(a.y, w1b[4*q+1], z1[r]);
        z0[r] = fmaf(a.z, w1a[4*q+2], z0[r]); z1[r] = fmaf(a.z, w1b[4*q+2], z1[r]);
        z0[r] = fmaf(a.w, w1a[4*q+3], z0[r]); z1[r] = fmaf(a.w, w1b[4*q+3], z1[r]);
      }
    }
    // reduce the 4 dim-quarters across the lane quad (VALU DPP, fixed order)
#pragma unroll
    for (int r = 0; r < ROWS; ++r) {
      z0[r] = dpp_add<DPP_XOR1>(z0[r]); z0[r] = dpp_add<DPP_XOR2>(z0[r]);
      z1[r] = dpp_add<DPP_XOR1>(z1[r]); z1[r] = dpp_add<DPP_XOR2>(z1[r]);
    }
    // lane dg of each quad owns 4 finals: (e=dg>>1, rows 4*(dg&1)..+3)
    {
      const bool ehi = (dg >> 1) != 0;
      const bool rhi = (dg & 1) != 0;
      const float bsel = ehi ? b1b : b1a;
      const int jsel = jp + (ehi ? 128 : 0);
      const int rbase = rhi ? 4 : 0;
#pragma unroll
      for (int m = 0; m < 4; ++m) {
        const float vhi = rhi ? z1[4 + m] : z1[m];
        const float vlo = rhi ? z0[4 + m] : z0[m];
        const float v = ehi ? vhi : vlo;          // compile-time reg indices
        sZ[(rbase + m) * ZS + jsel] = fast_tanh(v + bsel);
      }
    }
    __syncthreads();                      // B_b: z visible

    // ---- GEMM2: p[{2dp,2dp+1}][r] partial over 16 j's, 8 FMAs per quad ----
    float p0[ROWS], p1[ROWS];
#pragma unroll
    for (int r = 0; r < ROWS; ++r) { p0[r] = 0.0f; p1[r] = 0.0f; }
#pragma unroll
    for (int r = 0; r < ROWS; ++r) {
#pragma unroll
      for (int q = 0; q < 4; ++q) {
        const float4 zq = *(const float4*)&sZ[r * ZS + c * 16 + 4 * q];
        p0[r] = fmaf(zq.x, w2a[4*q+0], p0[r]); p1[r] = fmaf(zq.x, w2b[4*q+0], p1[r]);
        p0[r] = fmaf(zq.y, w2a[4*q+1], p0[r]); p1[r] = fmaf(zq.y, w2b[4*q+1], p1[r]);
        p0[r] = fmaf(zq.z, w2a[4*q+2], p0[r]); p1[r] = fmaf(zq.z, w2b[4*q+2], p1[r]);
        p0[r] = fmaf(zq.w, w2a[4*q+3], p0[r]); p1[r] = fmaf(zq.w, w2b[4*q+3], p1[r]);
      }
    }
    // reduce 4 chunk-low lanes (c_lo quad) via DPP
#pragma unroll
    for (int r = 0; r < ROWS; ++r) {
      p0[r] = dpp_add<DPP_XOR1>(p0[r]); p0[r] = dpp_add<DPP_XOR2>(p0[r]);
      p1[r] = dpp_add<DPP_XOR1>(p1[r]); p1[r] = dpp_add<DPP_XOR2>(p1[r]);
    }
    // lane c_lo owns 4 finals: (e2=c_lo>>1 -> d 2dp+e2, rows 4*(c_lo&1)..+3)
    {
      const bool ehi = (c_lo >> 1) != 0;
      const bool rhi = (c_lo & 1) != 0;
      const int dsel = 2 * dp + (ehi ? 1 : 0);
      const int rbase = rhi ? 4 : 0;
#pragma unroll
      for (int m = 0; m < 4; ++m) {
        const float vhi = rhi ? p1[4 + m] : p1[m];
        const float vlo = rhi ? p0[4 + m] : p0[m];
        const float v = ehi ? vhi : vlo;
        sRed[(c_hi * ROWS + rbase + m) * RS + dsel] = v;
      }
    }
    __syncthreads();                      // B_c: partials visible

    // owner (wv, d) combines the 4 chunk-high groups; fixed order
    float o = b2d;
#pragma unroll
    for (int ch = 0; ch < 4; ++ch) o += sRed[(ch * ROWS + wv) * RS + d];
    return o;
  };

  // Dormand-Prince 5(4) tableau (5th-order solution row); k' = dt*k prefold
  const float A10 = (float)(1.0 / 5.0);
  const float A20 = (float)(3.0 / 40.0),      A21 = (float)(9.0 / 40.0);
  const float A30 = (float)(44.0 / 45.0),     A31 = (float)(-56.0 / 15.0),
              A32 = (float)(32.0 / 9.0);
  const float A40 = (float)(19372.0 / 6561.0), A41 = (float)(-25360.0 / 2187.0),
              A42 = (float)(64448.0 / 6561.0), A43 = (float)(-212.0 / 729.0);
  const float A50 = (float)(9017.0 / 3168.0),  A51 = (float)(-355.0 / 33.0),
              A52 = (float)(46732.0 / 5247.0), A53 = (float)(49.0 / 176.0),
              A54 = (float)(-5103.0 / 18656.0);
  const float B0 = (float)(35.0 / 384.0),      B2 = (float)(500.0 / 1113.0),
              B3 = (float)(125.0 / 192.0),     B4 = (float)(-2187.0 / 6784.0),
              B5 = (float)(11.0 / 84.0);

  for (int ti = 0; ti < NT - 1; ++ti) {
    const float dt = (tt[ti + 1] - tt[ti]) * 0.25f;  // /SUBSTEPS, exact pow2
    for (int ss = 0; ss < 4; ++ss) {
      const float k0 = dt * feval(y);

      float yi = fmaf(A10, k0, y);
      const float k1 = dt * feval(yi);

      yi = y;
      yi = fmaf(A20, k0, yi); yi = fmaf(A21, k1, yi);
      const float k2 = dt * feval(yi);

      yi = y;
      yi = fmaf(A30, k0, yi); yi = fmaf(A31, k1, yi);
      yi = fmaf(A32, k2, yi);
      const float k3 = dt * feval(yi);

      yi = y;
      yi = fmaf(A40, k0, yi); yi = fmaf(A41, k1, yi);
      yi = fmaf(A42, k2, yi); yi = fmaf(A43, k3, yi);
      const float k4 = dt * feval(yi);

      yi = y;
      yi = fmaf(A50, k0, yi); yi = fmaf(A51, k1, yi);
      yi = fmaf(A52, k2, yi); yi = fmaf(A53, k3, yi);
      yi = fmaf(A54, k4, yi);
      const float k5 = dt * feval(yi);

      // y_new = y + B0*k'0 + B2*k'2 + B3*k'3 + B4*k'4 + B5*k'5   (B1 = 0)
      y = fmaf(B0, k0, y);
      y = fmaf(B2, k2, y);
      y = fmaf(B3, k3, y);
      y = fmaf(B4, k4, y);
      y = fmaf(B5, k5, y);
    }
    out[(size_t)(ti + 1) * NB * ND + row * ND + d] = y;
  }
}

extern "C" void kernel_launch(void* const* d_in, const int* in_sizes, int n_in,
                              void* d_out, int out_size, void* d_ws, size_t ws_size,
                              hipStream_t stream) {
  const float* y0 = (const float*)d_in[0];
  const float* tt = (const float*)d_in[1];
  const float* W1 = (const float*)d_in[2];
  const float* b1 = (const float*)d_in[3];
  const float* W2 = (const float*)d_in[4];
  const float* b2 = (const float*)d_in[5];
  float* out = (float*)d_out;

  hipLaunchKernelGGL(ode_kernel, dim3(GRID), dim3(THREADS), 0, stream,
                     y0, tt, W1, b1, W2, b2, out);
}

// Round 8
// 5713.020 us; speedup vs baseline: 2.2567x; 2.2567x over previous
//
#include <hip/hip_runtime.h>

#define NB 4096
#define ND 64
#define NH 256
#define NT 50
#define ROWS 8
#define THREADS 512
#define GRID (NB / ROWS)   // 512 blocks; ~1 resident/CU (2 sequential rounds)

// Padded LDS layouts: 16-element groups at stride-20 floats (80 B) so the 4
// group-selecting lanes (q4) hit disjoint bank quads {0-3}{20-23}{8-11}{28-31}.
#define YIS 84            // yi row stride: (d>>4)*20 + (d&15)
#define ZS  324           // z row stride: (j>>4)*20 + (j&15)
#define RRS 68            // sRed row stride
#define RJS (8 * RRS)     // 544: per-jhi block

__device__ __forceinline__ float fast_tanh(float x) {
  // tanh(x) = 1 - 2/(exp(2x)+1); safe at +-inf
  float e = __expf(2.0f * x);
  return 1.0f - 2.0f * __builtin_amdgcn_rcpf(e + 1.0f);
}

// quad-perm DPP butterfly add (VALU pipe, not LDS)
template <int CTRL>
__device__ __forceinline__ float dpp_add(float x) {
  int s = __builtin_amdgcn_update_dpp(0, __float_as_int(x), CTRL, 0xF, 0xF, true);
  return x + __int_as_float(s);
}
#define DPP_XOR1 0xB1  // quad_perm [1,0,3,2]
#define DPP_XOR2 0x4E  // quad_perm [2,3,0,1]

// waves_per_eu(2,2): RA budget 512/2 = 256 VGPR (demand ~195 -> no spill);
// achieved occupancy is 2 waves/EU regardless (same as r5's measured 24%),
// so the big register file is free. (r6 proved min=4 re-triggers the 64-reg
// squeeze; r5 proved max>=... the (2,*) min is what the scheduler grants.)
extern "C" __global__
__attribute__((amdgpu_flat_work_group_size(THREADS, THREADS)))
__attribute__((amdgpu_waves_per_eu(2, 2)))
void ode_kernel(const float* __restrict__ y0,
                const float* __restrict__ tt,
                const float* __restrict__ W1,
                const float* __restrict__ b1,
                const float* __restrict__ W2,
                const float* __restrict__ b2,
                float* __restrict__ out)
{
  __shared__ float sYI[ROWS * YIS];   // 672 floats
  __shared__ float sZ [ROWS * ZS];    // 2592 floats
  __shared__ float sRed[4 * RJS];     // 2176 floats  (21.8 KB total)

  const int tid  = threadIdx.x;
  const int wv   = tid >> 6;        // wave 0..7
  const int lane = tid & 63;
  const int d    = lane;            // state dim
  const int row  = (int)blockIdx.x * ROWS + wv;   // state row
  const int rh   = wv >> 2;         // row-half: both GEMMs work rows rh*4..+3
  const int q4   = lane & 3;        // G1 dgrp / G2 jlo (quad lane)
  const int jg   = (tid >> 2) & 63; // G1: j's 4jg..4jg+3
  const int jhi  = wv & 3;          // G2: j-supergroup
  const int dg2  = lane >> 2;       // G2: d's 4dg2..4dg2+3

  // ---- weights in registers (budget unlocked by waves_per_eu(2,2)) ----
  float w1_[16][4];   // [dd][jj] = W1[dgrp*16+dd][4jg+jj]
#pragma unroll
  for (int dd = 0; dd < 16; ++dd) {
    const float4 t = *(const float4*)&W1[(q4 * 16 + dd) * NH + 4 * jg];
    w1_[dd][0] = t.x; w1_[dd][1] = t.y; w1_[dd][2] = t.z; w1_[dd][3] = t.w;
  }
  const float4 b1v = *(const float4*)&b1[4 * jg];

  float w2_[16][4];   // [jj][dd] = W2[(jhi*4+jlo)*16+jj][4dg2+dd]
#pragma unroll
  for (int jj = 0; jj < 16; ++jj) {
    const float4 t = *(const float4*)&W2[((jhi * 4 + q4) * 16 + jj) * ND + 4 * dg2];
    w2_[jj][0] = t.x; w2_[jj][1] = t.y; w2_[jj][2] = t.z; w2_[jj][3] = t.w;
  }
  const float b2d = b2[d];

  // state: y[row][d]
  float y = y0[row * ND + d];
  out[row * ND + d] = y;

  // precomputed LDS pointers
  const int yi_woff = wv * YIS + (d >> 4) * 20 + (d & 15);
  const float* yib = &sYI[(rh * 4) * YIS + q4 * 20];                  // + r*YIS + 4q
  float*       zwb = &sZ[(rh * 4) * ZS + (jg >> 2) * 20 + 4 * (jg & 3)]; // + r*ZS
  const float* zrb = &sZ[(rh * 4) * ZS + (jhi * 4 + q4) * 20];        // + r*ZS + 4q
  float*       rwb = &sRed[jhi * RJS + (rh * 4) * RRS + 4 * dg2];     // + r*RRS
  const float* rob = &sRed[wv * RRS + d];                             // + jh*RJS

  // f(yi) = tanh(yi @ W1 + b1) @ W2 + b2, scalar slice per owner thread.
  // Schedule: write yi | Ba | G1 (16 b128 reads, 256 FMA, quad-DPP reduce,
  // pred tanh+store) | Bb | G2 (16 b128 reads, 256 FMA, quad-DPP reduce,
  // pred store) | Bc | owner combines 4 supergroups.
  auto feval = [&](float yiv) -> float {
    sYI[yi_woff] = yiv;
    __syncthreads();                     // Ba

    // ---- GEMM1: z[4 rows][4 j] partial over 16 dims (dgrp = q4) ----
    float z[4][4];
#pragma unroll
    for (int r = 0; r < 4; ++r)
#pragma unroll
      for (int jj = 0; jj < 4; ++jj) z[r][jj] = 0.0f;
#pragma unroll
    for (int r = 0; r < 4; ++r) {
#pragma unroll
      for (int q = 0; q < 4; ++q) {
        const float4 a = *(const float4*)(yib + r * YIS + 4 * q);
#pragma unroll
        for (int jj = 0; jj < 4; ++jj) {
          z[r][jj] = fmaf(a.x, w1_[4 * q + 0][jj], z[r][jj]);
          z[r][jj] = fmaf(a.y, w1_[4 * q + 1][jj], z[r][jj]);
          z[r][jj] = fmaf(a.z, w1_[4 * q + 2][jj], z[r][jj]);
          z[r][jj] = fmaf(a.w, w1_[4 * q + 3][jj], z[r][jj]);
        }
      }
    }
    // quad reduce over dgrp (deterministic butterfly, VALU pipe)
#pragma unroll
    for (int r = 0; r < 4; ++r)
#pragma unroll
      for (int jj = 0; jj < 4; ++jj)
        z[r][jj] = dpp_add<DPP_XOR2>(dpp_add<DPP_XOR1>(z[r][jj]));
    if (q4 == 0) {
#pragma unroll
      for (int r = 0; r < 4; ++r) {
        float4 zv;
        zv.x = fast_tanh(z[r][0] + b1v.x);
        zv.y = fast_tanh(z[r][1] + b1v.y);
        zv.z = fast_tanh(z[r][2] + b1v.z);
        zv.w = fast_tanh(z[r][3] + b1v.w);
        *(float4*)(zwb + r * ZS) = zv;
      }
    }
    __syncthreads();                     // Bb

    // ---- GEMM2: p[4 rows][4 d] partial over 16 j's (jgrp = jhi*4+q4) ----
    float p[4][4];
#pragma unroll
    for (int r = 0; r < 4; ++r)
#pragma unroll
      for (int dd = 0; dd < 4; ++dd) p[r][dd] = 0.0f;
#pragma unroll
    for (int r = 0; r < 4; ++r) {
#pragma unroll
      for (int q = 0; q < 4; ++q) {
        const float4 a = *(const float4*)(zrb + r * ZS + 4 * q);
#pragma unroll
        for (int dd = 0; dd < 4; ++dd) {
          p[r][dd] = fmaf(a.x, w2_[4 * q + 0][dd], p[r][dd]);
          p[r][dd] = fmaf(a.y, w2_[4 * q + 1][dd], p[r][dd]);
          p[r][dd] = fmaf(a.z, w2_[4 * q + 2][dd], p[r][dd]);
          p[r][dd] = fmaf(a.w, w2_[4 * q + 3][dd], p[r][dd]);
        }
      }
    }
#pragma unroll
    for (int r = 0; r < 4; ++r)
#pragma unroll
      for (int dd = 0; dd < 4; ++dd)
        p[r][dd] = dpp_add<DPP_XOR2>(dpp_add<DPP_XOR1>(p[r][dd]));
    if (q4 == 0) {
#pragma unroll
      for (int r = 0; r < 4; ++r)
        *(float4*)(rwb + r * RRS) = make_float4(p[r][0], p[r][1], p[r][2], p[r][3]);
    }
    __syncthreads();                     // Bc

    // owner (wv, d): combine 4 j-supergroups, fixed order
    float o = b2d;
#pragma unroll
    for (int jh = 0; jh < 4; ++jh) o += rob[jh * RJS];
    return o;
  };

  // Dormand-Prince 5(4) tableau (5th-order solution row)
  const float A10 = (float)(1.0 / 5.0);
  const float A20 = (float)(3.0 / 40.0),      A21 = (float)(9.0 / 40.0);
  const float A30 = (float)(44.0 / 45.0),     A31 = (float)(-56.0 / 15.0),
              A32 = (float)(32.0 / 9.0);
  const float A40 = (float)(19372.0 / 6561.0), A41 = (float)(-25360.0 / 2187.0),
              A42 = (float)(64448.0 / 6561.0), A43 = (float)(-212.0 / 729.0);
  const float A50 = (float)(9017.0 / 3168.0),  A51 = (float)(-355.0 / 33.0),
              A52 = (float)(46732.0 / 5247.0), A53 = (float)(49.0 / 176.0),
              A54 = (float)(-5103.0 / 18656.0);
  const float B0 = (float)(35.0 / 384.0),      B2 = (float)(500.0 / 1113.0),
              B3 = (float)(125.0 / 192.0),     B4 = (float)(-2187.0 / 6784.0),
              B5 = (float)(11.0 / 84.0);

  for (int ti = 0; ti < NT - 1; ++ti) {
    const float dt = (tt[ti + 1] - tt[ti]) * 0.25f;  // /SUBSTEPS, exact pow2
    for (int ss = 0; ss < 4; ++ss) {
      const float k0 = feval(y);

      float yi = fmaf(dt * A10, k0, y);
      const float k1 = feval(yi);

      yi = y;
      yi = fmaf(dt * A20, k0, yi); yi = fmaf(dt * A21, k1, yi);
      const float k2 = feval(yi);

      yi = y;
      yi = fmaf(dt * A30, k0, yi); yi = fmaf(dt * A31, k1, yi);
      yi = fmaf(dt * A32, k2, yi);
      const float k3 = feval(yi);

      yi = y;
      yi = fmaf(dt * A40, k0, yi); yi = fmaf(dt * A41, k1, yi);
      yi = fmaf(dt * A42, k2, yi); yi = fmaf(dt * A43, k3, yi);
      const float k4 = feval(yi);

      yi = y;
      yi = fmaf(dt * A50, k0, yi); yi = fmaf(dt * A51, k1, yi);
      yi = fmaf(dt * A52, k2, yi); yi = fmaf(dt * A53, k3, yi);
      yi = fmaf(dt * A54, k4, yi);
      const float k5 = feval(yi);

      // y_new = y + dt*(B0*k0 + B2*k2 + B3*k3 + B4*k4 + B5*k5)   (B1 = 0)
      y = fmaf(dt * B0, k0, y);
      y = fmaf(dt * B2, k2, y);
      y = fmaf(dt * B3, k3, y);
      y = fmaf(dt * B4, k4, y);
      y = fmaf(dt * B5, k5, y);
    }
    out[(size_t)(ti + 1) * NB * ND + row * ND + d] = y;
  }
}

extern "C" void kernel_launch(void* const* d_in, const int* in_sizes, int n_in,
                              void* d_out, int out_size, void* d_ws, size_t ws_size,
                              hipStream_t stream) {
  const float* y0 = (const float*)d_in[0];
  const float* tt = (const float*)d_in[1];
  const float* W1 = (const float*)d_in[2];
  const float* b1 = (const float*)d_in[3];
  const float* W2 = (const float*)d_in[4];
  const float* b2 = (const float*)d_in[5];
  float* out = (float*)d_out;

  hipLaunchKernelGGL(ode_kernel, dim3(GRID), dim3(THREADS), 0, stream,
                     y0, tt, W1, b1, W2, b2, out);
}